// Round 6
// baseline (202.493 us; speedup 1.0000x reference)
//
#include <hip/hip_runtime.h>

// YOLO-v1 loss, N=4096, S=14 grid, 30 channels/cell. ~176 MB in, 5 floats out.
// R1: killed same-line atomicAdd fan-in (188us) -> 70us.
// R2/R4: occupancy 40->67% changed nothing -> not residency-bound.
// R5: barrier-free wave-autonomous chunks + obj-gated tcls -> 56us. Waves
//     still ~90% stalled: explicit waitcnt(0) per chunk + serially-dependent
//     gated tcls loads cap in-flight at ~1 chunk/wave.
// R6: cross-iteration register prefetch (pred/obj/tbox of chunk k+1 issued
//     during chunk k), obj via single load + shfl broadcast so tcls gating
//     predicate is pre-resident, NO explicit waitcnt (compiler emits precise
//     vmcnt leaving prefetch in flight). launch_bounds(256,6), NBLK=1536.

#define NBATCH   4096
#define CELLS    (NBATCH * 14 * 14)     // 802816
#define THREADS  256
#define NBLK     1536                   // 6 blocks/CU resident, uniform start
#define NWAVES   (NBLK * 4)             // 6144
#define CHUNKS   (CELLS / 32)           // 25088 chunks of 32 cells (4-5/wave)
#define L_COORD  5.0f
#define L_NOOBJ  0.5f

__global__ __launch_bounds__(THREADS, 6) void yolo_main(
    const float* __restrict__ pred,    // [CELLS][30]
    const float* __restrict__ tbox,    // [CELLS][4]
    const float* __restrict__ tcls,    // [CELLS][20]
    const int*   __restrict__ objmap,  // [CELLS]
    float4*      __restrict__ part)    // [NBLK]
{
    __shared__ float lds[4 * 960];     // 3840 B per wave: 32 cells x 30 floats
    __shared__ float red[4][4];

    const int tid  = threadIdx.x;
    const int wv   = tid >> 6;
    const int lane = tid & 63;
    float* seg = &lds[wv * 960];
    float4* s4 = (float4*)seg;

    // cls-pass lane->cell mapping (i = lane, lane+64, lane+128; cell = i/5)
    const int i1  = lane + 64, i2 = lane + 128;
    const int cc0 = lane / 5;
    const int cc1 = i1 / 5;
    const int cc2 = (lane < 32) ? (i2 / 5) : 0;
    const int ch0a = (lane - cc0 * 5) * 4;
    const int ch0b = (i1   - cc1 * 5) * 4;
    const int ch0c = (i2   - cc2 * 5) * 4;
    const int bcell = lane >> 1;       // per-box pairing: 2 lanes per cell
    const int box   = lane & 1;
    const int l31   = lane & 31;
    const float invS = 1.0f / 14.0f;

    float acc_reg = 0.f, acc_cont = 0.f, acc_noobj = 0.f, acc_cls = 0.f;

    const int gw0 = blockIdx.x * 4 + wv;

    // ---- prologue: prefetch chunk gw0 ----
    float4 pv0, pv1, pv2, pv3;
    float4 tbv;
    int    ov;
    {
        const size_t cb = (size_t)gw0 * 32;
        const float4* p4 = (const float4*)pred + (size_t)gw0 * 240;
        ov  = objmap[cb + l31];
        tbv = ((const float4*)tbox)[cb + bcell];
        pv0 = p4[lane];
        pv1 = p4[i1];
        pv2 = p4[i2];
        if (lane < 48) pv3 = p4[lane + 192];
    }

    for (int c = gw0; c < CHUNKS; c += NWAVES) {
        // current chunk values out of the prefetch regs (SSA; compiler renames)
        float4 a0 = pv0, a1 = pv1, a2 = pv2, a3 = pv3;
        float4 tb = tbv;
        int    ob = ov;

        // ---- issue next chunk's prefetch early (stays in flight) ----
        const int cn = c + NWAVES;
        if (cn < CHUNKS) {
            const size_t cb = (size_t)cn * 32;
            const float4* p4 = (const float4*)pred + (size_t)cn * 240;
            ov  = objmap[cb + l31];
            tbv = ((const float4*)tbox)[cb + bcell];
            pv0 = p4[lane];
            pv1 = p4[i1];
            pv2 = p4[i2];
            if (lane < 48) pv3 = p4[lane + 192];
        }

        // ---- stage current pred into wave-private LDS segment ----
        // (compiler waits vmcnt only for a0..a3; prefetch stays in flight;
        //  same-wave DS in-order makes write->read safe without barriers)
        s4[lane] = a0;
        s4[i1]   = a1;
        s4[i2]   = a2;
        if (lane < 48) s4[lane + 192] = a3;

        // obj broadcast: lanes 0..31 hold cells 0..31 of this chunk
        const int o0  = __shfl(ob, cc0);
        const int o1  = __shfl(ob, cc1);
        const int o2  = __shfl(ob, cc2);
        const int obx = __shfl(ob, bcell);

        // ---- gated tcls loads: predicate already resident -> issue now,
        //      consumed after the box pass (latency hidden) ----
        float4 t0, t1, t2;
        const float4* t4 = (const float4*)tcls + (size_t)c * 160;
        const bool g0 = (o0 != 0);
        const bool g1 = (o1 != 0);
        const bool g2 = (lane < 32) && (o2 != 0);
        if (g0) t0 = t4[lane];
        if (g1) t1 = t4[i1];
        if (g2) t2 = t4[i2];

        // ---- per-box pass: thread = (cell, box), partner via shfl_xor ----
        {
            const float* pp = &seg[bcell * 30 + box * 5];
            float x = pp[0], y = pp[1], w = pp[2], h = pp[3], conf = pp[4];

            if (!obx) acc_noobj += conf * conf;   // pair covers c1^2 + c2^2

            float txc = tb.x * invS, tyc = tb.y * invS;
            float tx1 = txc - 0.5f * tb.z, ty1 = tyc - 0.5f * tb.w;
            float tx2 = txc + 0.5f * tb.z, ty2 = tyc + 0.5f * tb.w;
            float ta  = (tx2 - tx1) * (ty2 - ty1);

            float ax1 = x * invS - 0.5f * w, ay1 = y * invS - 0.5f * h;
            float ax2 = x * invS + 0.5f * w, ay2 = y * invS + 0.5f * h;
            float a1b = (ax2 - ax1) * (ay2 - ay1);
            float iw  = fmaxf(fminf(ax2, tx2) - fmaxf(ax1, tx1), 0.f);
            float ih  = fmaxf(fminf(ay2, ty2) - fmaxf(ay1, ty1), 0.f);
            float inter = iw * ih;
            float iou   = inter / (a1b + ta - inter);

            float iou_other = __shfl_xor(iou, 1);
            // reference: take1 = iou1 > iou2
            bool win = (box == 0) ? (iou > iou_other) : !(iou_other > iou);

            if (win && obx) {
                float dx = x - tb.x, dy = y - tb.y;
                float dw = sqrtf(w) - sqrtf(tb.z);
                float dh = sqrtf(h) - sqrtf(tb.w);
                acc_reg  += dx*dx + dy*dy + dw*dw + dh*dh;
                float dc  = conf - iou;
                acc_cont += dc * dc;
            }
        }

        // ---- cls pass: tcls regs have been in flight through the box pass ----
        {
            float cl = 0.f;
            if (g0) {
                const float* pc = &seg[cc0 * 30 + 10 + ch0a];
                float d0 = pc[0]-t0.x, d1 = pc[1]-t0.y, d2 = pc[2]-t0.z, d3 = pc[3]-t0.w;
                cl += d0*d0 + d1*d1 + d2*d2 + d3*d3;
            }
            if (g1) {
                const float* pc = &seg[cc1 * 30 + 10 + ch0b];
                float d0 = pc[0]-t1.x, d1 = pc[1]-t1.y, d2 = pc[2]-t1.z, d3 = pc[3]-t1.w;
                cl += d0*d0 + d1*d1 + d2*d2 + d3*d3;
            }
            if (g2) {
                const float* pc = &seg[cc2 * 30 + 10 + ch0c];
                float d0 = pc[0]-t2.x, d1 = pc[1]-t2.y, d2 = pc[2]-t2.z, d3 = pc[3]-t2.w;
                cl += d0*d0 + d1*d1 + d2*d2 + d3*d3;
            }
            acc_cls += cl;
        }
    }

    // ---- final reduction (only barrier in the kernel) ----
    #pragma unroll
    for (int off = 32; off > 0; off >>= 1) {
        acc_reg   += __shfl_down(acc_reg,   off);
        acc_cont  += __shfl_down(acc_cont,  off);
        acc_noobj += __shfl_down(acc_noobj, off);
        acc_cls   += __shfl_down(acc_cls,   off);
    }
    if (lane == 0) {
        red[wv][0] = acc_reg;
        red[wv][1] = acc_cont;
        red[wv][2] = acc_noobj;
        red[wv][3] = acc_cls;
    }
    __syncthreads();
    if (tid == 0) {
        float4 p;
        p.x = red[0][0] + red[1][0] + red[2][0] + red[3][0];
        p.y = red[0][1] + red[1][1] + red[2][1] + red[3][1];
        p.z = red[0][2] + red[1][2] + red[2][2] + red[3][2];
        p.w = red[0][3] + red[1][3] + red[2][3] + red[3][3];
        part[blockIdx.x] = p;
    }
}

__global__ __launch_bounds__(1024) void yolo_reduce(
    const float4* __restrict__ part, float* __restrict__ out)
{
    __shared__ float red[16][4];
    float r = 0.f, c = 0.f, n = 0.f, cl = 0.f;
    for (int i = threadIdx.x; i < NBLK; i += 1024) {   // <=2 loads
        float4 p = part[i];
        r += p.x; c += p.y; n += p.z; cl += p.w;
    }
    #pragma unroll
    for (int off = 32; off > 0; off >>= 1) {
        r  += __shfl_down(r,  off);
        c  += __shfl_down(c,  off);
        n  += __shfl_down(n,  off);
        cl += __shfl_down(cl, off);
    }
    const int wave = threadIdx.x >> 6, lane = threadIdx.x & 63;
    if (lane == 0) {
        red[wave][0] = r; red[wave][1] = c; red[wave][2] = n; red[wave][3] = cl;
    }
    __syncthreads();
    if (threadIdx.x == 0) {
        float R = 0.f, C = 0.f, Nn = 0.f, Cl = 0.f;
        #pragma unroll
        for (int w = 0; w < 16; ++w) {
            R += red[w][0]; C += red[w][1]; Nn += red[w][2]; Cl += red[w][3];
        }
        const float invN = 1.0f / (float)NBATCH;
        float reg   = L_COORD * R  * invN;
        float cont  =           C  * invN;
        float noobj = L_NOOBJ * Nn * invN;
        float cls   =           Cl * invN;
        out[0] = reg + cont + noobj + cls;
        out[1] = reg;
        out[2] = cont;
        out[3] = noobj;
        out[4] = cls;
    }
}

extern "C" void kernel_launch(void* const* d_in, const int* in_sizes, int n_in,
                              void* d_out, int out_size, void* d_ws, size_t ws_size,
                              hipStream_t stream) {
    const float* pred   = (const float*)d_in[0];
    const float* tbox   = (const float*)d_in[1];
    const float* tcls   = (const float*)d_in[2];
    const int*   objmap = (const int*)  d_in[3];
    float4* part = (float4*)d_ws;      // NBLK * 16 B, every slot written
    float*  out  = (float*)d_out;

    yolo_main<<<NBLK, THREADS, 0, stream>>>(pred, tbox, tcls, objmap, part);
    yolo_reduce<<<1, 1024, 0, stream>>>(part, out);
}